// Round 1
// baseline (4158.321 us; speedup 1.0000x reference)
//
#include <hip/hip_runtime.h>
#include <math.h>

// EdgeToNodeAttention: round 0 — correct fp32 baseline.
// Pipeline: memset stats -> Q=x@W_Q+b -> fused(K-proj,score) -> seg_max(atomic)
//           -> seg_sum(atomic) -> fused(V-proj, alpha*phi scatter-add) -> out=accum@W_O+b
#define NN 50000
#define NE 800000
#define D  128
#define NH 8

// monotone float<->uint key for atomicMax on signed floats
__device__ __forceinline__ unsigned fkey(float f) {
  unsigned b = __float_as_uint(f);
  return (b & 0x80000000u) ? ~b : (b | 0x80000000u);
}
__device__ __forceinline__ float funkey(unsigned k) {
  unsigned b = (k & 0x80000000u) ? (k & 0x7FFFFFFFu) : ~k;
  return __uint_as_float(b);
}

// Stage A[row0..row0+64) x 128 into LDS transposed: As[k][m]. Pad 65 to break
// power-of-2 bank strides. Zero-fill rows >= M.
__device__ __forceinline__ void load_tile(const float* __restrict__ A, int row0, int M,
                                          float (*As)[65], int tid) {
#pragma unroll
  for (int i = 0; i < 8; ++i) {
    int p = tid + i * 256;        // float4 index within 64x128 tile
    int r = p >> 5;               // row in tile
    int c = (p & 31) << 2;        // col (multiple of 4)
    float4 v = make_float4(0.f, 0.f, 0.f, 0.f);
    int row = row0 + r;
    if (row < M) v = *(const float4*)(A + (size_t)row * D + c);
    As[c + 0][r] = v.x;
    As[c + 1][r] = v.y;
    As[c + 2][r] = v.z;
    As[c + 3][r] = v.w;
  }
}

// acc[4][8]: rows ty*4..+4 of tile, cols tx*8..+8 of B (B is 128x128 row-major, L2-resident)
__device__ __forceinline__ void gemm_core(const float (*As)[65], const float* __restrict__ B,
                                          int ty, int tx, float acc[4][8]) {
#pragma unroll 8
  for (int k = 0; k < 128; ++k) {
    float a[4];
#pragma unroll
    for (int r = 0; r < 4; ++r) a[r] = As[k][ty * 4 + r];
    float4 b0 = *(const float4*)(B + k * D + tx * 8);
    float4 b1 = *(const float4*)(B + k * D + tx * 8 + 4);
    float b[8] = {b0.x, b0.y, b0.z, b0.w, b1.x, b1.y, b1.z, b1.w};
#pragma unroll
    for (int r = 0; r < 4; ++r)
#pragma unroll
      for (int c = 0; c < 8; ++c) acc[r][c] += a[r] * b[c];
  }
}

__global__ __launch_bounds__(256, 4) void gemm_bias_k(const float* __restrict__ A,
    const float* __restrict__ B, const float* __restrict__ bias,
    float* __restrict__ C, int M) {
  __shared__ float As[128][65];
  int tid = threadIdx.x;
  int row0 = blockIdx.x * 64;
  load_tile(A, row0, M, As, tid);
  __syncthreads();
  int ty = tid >> 4, tx = tid & 15;
  float acc[4][8] = {};
  gemm_core(As, B, ty, tx, acc);
  float4 ba = *(const float4*)(bias + tx * 8);
  float4 bb = *(const float4*)(bias + tx * 8 + 4);
#pragma unroll
  for (int r = 0; r < 4; ++r) {
    int row = row0 + ty * 4 + r;
    if (row < M) {
      float4 o0 = make_float4(acc[r][0] + ba.x, acc[r][1] + ba.y,
                              acc[r][2] + ba.z, acc[r][3] + ba.w);
      float4 o1 = make_float4(acc[r][4] + bb.x, acc[r][5] + bb.y,
                              acc[r][6] + bb.z, acc[r][7] + bb.w);
      *(float4*)(C + (size_t)row * D + tx * 8) = o0;
      *(float4*)(C + (size_t)row * D + tx * 8 + 4) = o1;
    }
  }
}

// fused K = edge_attr@W_K + b_K ; score[e,h] = (K[e,h*16:+16] . Q[j[e],h*16:+16]) / 4
__global__ __launch_bounds__(256, 4) void kscore_k(const float* __restrict__ EA,
    const float* __restrict__ WK, const float* __restrict__ bK,
    const float* __restrict__ Q, const int* __restrict__ jidx,
    float* __restrict__ scores) {
  __shared__ float As[128][65];
  int tid = threadIdx.x;
  int e0 = blockIdx.x * 64;
  load_tile(EA, e0, NE, As, tid);
  __syncthreads();
  int ty = tid >> 4, tx = tid & 15;
  float acc[4][8] = {};
  gemm_core(As, WK, ty, tx, acc);
  float4 ka = *(const float4*)(bK + tx * 8);
  float4 kb = *(const float4*)(bK + tx * 8 + 4);
  int h = tx >> 1;  // this thread's 8 cols live inside head h
#pragma unroll
  for (int r = 0; r < 4; ++r) {
    int e = e0 + ty * 4 + r;
    int jn = jidx[e];
    float4 qa = *(const float4*)(Q + (size_t)jn * D + tx * 8);
    float4 qb = *(const float4*)(Q + (size_t)jn * D + tx * 8 + 4);
    float p = (acc[r][0] + ka.x) * qa.x + (acc[r][1] + ka.y) * qa.y +
              (acc[r][2] + ka.z) * qa.z + (acc[r][3] + ka.w) * qa.w +
              (acc[r][4] + kb.x) * qb.x + (acc[r][5] + kb.y) * qb.y +
              (acc[r][6] + kb.z) * qb.z + (acc[r][7] + kb.w) * qb.w;
    p += __shfl_xor(p, 1);  // combine the two half-head partials
    if ((tx & 1) == 0) scores[(size_t)e * NH + h] = p * 0.25f;
  }
}

__global__ __launch_bounds__(256) void segmax_k(const float* __restrict__ scores,
    const int* __restrict__ jidx, unsigned* __restrict__ keys) {
  int t = blockIdx.x * 256 + threadIdx.x;  // t < NE*NH
  int e = t >> 3, h = t & 7;
  atomicMax(&keys[(size_t)jidx[e] * NH + h], fkey(scores[t]));
}

__global__ __launch_bounds__(256) void segsum_k(const float* __restrict__ scores,
    const int* __restrict__ jidx, const unsigned* __restrict__ keys,
    float* __restrict__ segsum) {
  int t = blockIdx.x * 256 + threadIdx.x;
  int e = t >> 3, h = t & 7;
  int jn = jidx[e];
  float ex = __expf(scores[t] - funkey(keys[(size_t)jn * NH + h]));
  atomicAdd(&segsum[(size_t)jn * NH + h], ex);
}

// fused V = edge_attr@W_V + b_V ; accum[j[e],:] += alpha[e,h]*phi[e]*V[e,:]
__global__ __launch_bounds__(256, 4) void vagg_k(const float* __restrict__ EA,
    const float* __restrict__ WV, const float* __restrict__ bV,
    const float* __restrict__ scores, const int* __restrict__ jidx,
    const unsigned* __restrict__ keys, const float* __restrict__ segsum,
    const float* __restrict__ elen, float* __restrict__ accum) {
  __shared__ float As[128][65];
  int tid = threadIdx.x;
  int e0 = blockIdx.x * 64;
  load_tile(EA, e0, NE, As, tid);
  __syncthreads();
  int ty = tid >> 4, tx = tid & 15;
  float acc[4][8] = {};
  gemm_core(As, WV, ty, tx, acc);
  float4 va = *(const float4*)(bV + tx * 8);
  float4 vb = *(const float4*)(bV + tx * 8 + 4);
  int h = tx >> 1;
#pragma unroll
  for (int r = 0; r < 4; ++r) {
    int e = e0 + ty * 4 + r;
    int jn = jidx[e];
    float s = scores[(size_t)e * NH + h];
    float m = funkey(keys[(size_t)jn * NH + h]);
    float ssum = segsum[(size_t)jn * NH + h];
    float len = elen[e];
    float phi = 0.5f * (cosf(len * 0.628318530717958647f) + 1.0f);  // pi/5
    float w = __expf(s - m) / ssum * phi;
    float* dst = accum + (size_t)jn * D + tx * 8;
    atomicAdd(dst + 0, (acc[r][0] + va.x) * w);
    atomicAdd(dst + 1, (acc[r][1] + va.y) * w);
    atomicAdd(dst + 2, (acc[r][2] + va.z) * w);
    atomicAdd(dst + 3, (acc[r][3] + va.w) * w);
    atomicAdd(dst + 4, (acc[r][4] + vb.x) * w);
    atomicAdd(dst + 5, (acc[r][5] + vb.y) * w);
    atomicAdd(dst + 6, (acc[r][6] + vb.z) * w);
    atomicAdd(dst + 7, (acc[r][7] + vb.w) * w);
  }
}

extern "C" void kernel_launch(void* const* d_in, const int* in_sizes, int n_in,
                              void* d_out, int out_size, void* d_ws, size_t ws_size,
                              hipStream_t stream) {
  const float* x     = (const float*)d_in[0];
  const int*   eidx  = (const int*)d_in[1];
  const int*   jidx  = eidx + NE;            // edge_index[1] = target nodes
  const float* eattr = (const float*)d_in[2];
  const float* elen  = (const float*)d_in[3];
  const float* W_Q   = (const float*)d_in[4];
  const float* b_Q   = (const float*)d_in[5];
  const float* W_K   = (const float*)d_in[6];
  const float* b_K   = (const float*)d_in[7];
  const float* W_V   = (const float*)d_in[8];
  const float* b_V   = (const float*)d_in[9];
  const float* W_O   = (const float*)d_in[10];
  const float* b_O   = (const float*)d_in[11];
  float* out = (float*)d_out;

  float* ws = (float*)d_ws;
  float*    Q      = ws;                                   // NN*D
  float*    scores = Q + (size_t)NN * D;                   // NE*NH
  unsigned* keys   = (unsigned*)(scores + (size_t)NE * NH);// NN*NH
  float*    segsum = (float*)(keys + (size_t)NN * NH);     // NN*NH
  float*    accum  = segsum + (size_t)NN * NH;             // NN*D

  // zero keys+segsum+accum (contiguous)
  hipMemsetAsync(keys, 0,
                 ((size_t)NN * NH * 2 + (size_t)NN * D) * sizeof(float), stream);

  gemm_bias_k<<<(NN + 63) / 64, 256, 0, stream>>>(x, W_Q, b_Q, Q, NN);
  kscore_k<<<NE / 64, 256, 0, stream>>>(eattr, W_K, b_K, Q, jidx, scores);
  segmax_k<<<(NE * NH) / 256, 256, 0, stream>>>(scores, jidx, keys);
  segsum_k<<<(NE * NH) / 256, 256, 0, stream>>>(scores, jidx, keys, segsum);
  vagg_k<<<NE / 64, 256, 0, stream>>>(eattr, W_V, b_V, scores, jidx, keys,
                                      segsum, elen, accum);
  gemm_bias_k<<<(NN + 63) / 64, 256, 0, stream>>>(accum, W_O, b_O, out, NN);
}

// Round 2
// 1979.745 us; speedup vs baseline: 2.1004x; 2.1004x over previous
//
#include <hip/hip_runtime.h>
#include <math.h>

// R1: kill vagg atomics. CSR by target node -> per-node softmax stats (no
// atomics) -> V-proj writes weighted bf16 rows at CSR slots -> contiguous
// per-node gather -> O-GEMM.
#define NN 50000
#define NE 800000
#define D  128
#define NH 8

__device__ __forceinline__ unsigned short f2bf(float f) {  // RNE
  unsigned x = __float_as_uint(f);
  unsigned r = ((x >> 16) & 1u) + 0x7FFFu;
  return (unsigned short)((x + r) >> 16);
}

// Stage A[row0..row0+64) x 128 into LDS transposed As[k][m]; pad 65.
__device__ __forceinline__ void load_tile(const float* __restrict__ A, int row0, int M,
                                          float (*As)[65], int tid) {
#pragma unroll
  for (int i = 0; i < 8; ++i) {
    int p = tid + i * 256;
    int r = p >> 5;
    int c = (p & 31) << 2;
    float4 v = make_float4(0.f, 0.f, 0.f, 0.f);
    int row = row0 + r;
    if (row < M) v = *(const float4*)(A + (size_t)row * D + c);
    As[c + 0][r] = v.x;
    As[c + 1][r] = v.y;
    As[c + 2][r] = v.z;
    As[c + 3][r] = v.w;
  }
}

__device__ __forceinline__ void gemm_core(const float (*As)[65], const float* __restrict__ B,
                                          int ty, int tx, float acc[4][8]) {
#pragma unroll 8
  for (int k = 0; k < 128; ++k) {
    float a[4];
#pragma unroll
    for (int r = 0; r < 4; ++r) a[r] = As[k][ty * 4 + r];
    float4 b0 = *(const float4*)(B + k * D + tx * 8);
    float4 b1 = *(const float4*)(B + k * D + tx * 8 + 4);
    float b[8] = {b0.x, b0.y, b0.z, b0.w, b1.x, b1.y, b1.z, b1.w};
#pragma unroll
    for (int r = 0; r < 4; ++r)
#pragma unroll
      for (int c = 0; c < 8; ++c) acc[r][c] += a[r] * b[c];
  }
}

__global__ __launch_bounds__(256, 4) void gemm_bias_k(const float* __restrict__ A,
    const float* __restrict__ B, const float* __restrict__ bias,
    float* __restrict__ C, int M) {
  __shared__ float As[128][65];
  int tid = threadIdx.x;
  int row0 = blockIdx.x * 64;
  load_tile(A, row0, M, As, tid);
  __syncthreads();
  int ty = tid >> 4, tx = tid & 15;
  float acc[4][8] = {};
  gemm_core(As, B, ty, tx, acc);
  float4 ba = *(const float4*)(bias + tx * 8);
  float4 bb = *(const float4*)(bias + tx * 8 + 4);
#pragma unroll
  for (int r = 0; r < 4; ++r) {
    int row = row0 + ty * 4 + r;
    if (row < M) {
      float4 o0 = make_float4(acc[r][0] + ba.x, acc[r][1] + ba.y,
                              acc[r][2] + ba.z, acc[r][3] + ba.w);
      float4 o1 = make_float4(acc[r][4] + bb.x, acc[r][5] + bb.y,
                              acc[r][6] + bb.z, acc[r][7] + bb.w);
      *(float4*)(C + (size_t)row * D + tx * 8) = o0;
      *(float4*)(C + (size_t)row * D + tx * 8 + 4) = o1;
    }
  }
}

// K = EA@W_K + b_K ; scores[e,h] = K.Q[j[e]] per head / 4
__global__ __launch_bounds__(256, 4) void kscore_k(const float* __restrict__ EA,
    const float* __restrict__ WK, const float* __restrict__ bK,
    const float* __restrict__ Q, const int* __restrict__ jidx,
    float* __restrict__ scores) {
  __shared__ float As[128][65];
  int tid = threadIdx.x;
  int e0 = blockIdx.x * 64;
  load_tile(EA, e0, NE, As, tid);
  __syncthreads();
  int ty = tid >> 4, tx = tid & 15;
  float acc[4][8] = {};
  gemm_core(As, WK, ty, tx, acc);
  float4 ka = *(const float4*)(bK + tx * 8);
  float4 kb = *(const float4*)(bK + tx * 8 + 4);
  int h = tx >> 1;
#pragma unroll
  for (int r = 0; r < 4; ++r) {
    int e = e0 + ty * 4 + r;
    int jn = jidx[e];
    float4 qa = *(const float4*)(Q + (size_t)jn * D + tx * 8);
    float4 qb = *(const float4*)(Q + (size_t)jn * D + tx * 8 + 4);
    float p = (acc[r][0] + ka.x) * qa.x + (acc[r][1] + ka.y) * qa.y +
              (acc[r][2] + ka.z) * qa.z + (acc[r][3] + ka.w) * qa.w +
              (acc[r][4] + kb.x) * qb.x + (acc[r][5] + kb.y) * qb.y +
              (acc[r][6] + kb.z) * qb.z + (acc[r][7] + kb.w) * qb.w;
    p += __shfl_xor(p, 1);
    if ((tx & 1) == 0) scores[(size_t)e * NH + h] = p * 0.25f;
  }
}

// ---- CSR build ----
__global__ __launch_bounds__(256) void hist_k(const int* __restrict__ jidx,
                                              int* __restrict__ cnt) {
  int e = blockIdx.x * 256 + threadIdx.x;
  atomicAdd(&cnt[jidx[e]], 1);
}

__global__ __launch_bounds__(1024) void scan_k(const int* __restrict__ cnt,
    int* __restrict__ offs, int* __restrict__ cursor) {
  __shared__ int part[1024];
  const int CH = 49;  // 49*1024 >= NN
  int t = threadIdx.x;
  int base = t * CH;
  int s = 0;
  for (int i = 0; i < CH; ++i) {
    int idx = base + i;
    if (idx < NN) s += cnt[idx];
  }
  part[t] = s;
  __syncthreads();
  for (int off = 1; off < 1024; off <<= 1) {
    int v = (t >= off) ? part[t - off] : 0;
    __syncthreads();
    part[t] += v;
    __syncthreads();
  }
  int run = (t == 0) ? 0 : part[t - 1];
  for (int i = 0; i < CH; ++i) {
    int idx = base + i;
    if (idx < NN) {
      offs[idx] = run;
      cursor[idx] = run;
      run += cnt[idx];
    }
  }
  if (t == 1023) offs[NN] = run;
}

__global__ __launch_bounds__(256) void scatter_k(const int* __restrict__ jidx,
    int* __restrict__ cursor, int* __restrict__ elist, int* __restrict__ pos) {
  int e = blockIdx.x * 256 + threadIdx.x;
  int p = atomicAdd(&cursor[jidx[e]], 1);
  elist[p] = e;
  pos[e] = p;
}

// per-node softmax stats from CSR: m[n][h], den[n][h]. block=128 (8 heads x 16 lanes)
__global__ __launch_bounds__(128) void stats_k(const float* __restrict__ scores,
    const int* __restrict__ offs, const int* __restrict__ elist,
    float* __restrict__ m, float* __restrict__ den) {
  int n = blockIdx.x;
  int tid = threadIdx.x;
  int h = tid >> 4, l = tid & 15;
  int o0 = offs[n], o1 = offs[n + 1];
  float mx = -INFINITY;
  for (int i = o0 + l; i < o1; i += 16)
    mx = fmaxf(mx, scores[(size_t)elist[i] * NH + h]);
#pragma unroll
  for (int d = 1; d < 16; d <<= 1) mx = fmaxf(mx, __shfl_xor(mx, d));
  float sm = 0.f;
  for (int i = o0 + l; i < o1; i += 16)
    sm += __expf(scores[(size_t)elist[i] * NH + h] - mx);
#pragma unroll
  for (int d = 1; d < 16; d <<= 1) sm += __shfl_xor(sm, d);
  if (l == 0) {
    m[(size_t)n * NH + h] = mx;
    den[(size_t)n * NH + h] = sm;
  }
}

// V = EA@W_V + b_V ; w = alpha*phi ; Vw[pos[e]] = bf16(w*V) (CSR-ordered rows)
__global__ __launch_bounds__(256, 4) void vw_k(const float* __restrict__ EA,
    const float* __restrict__ WV, const float* __restrict__ bV,
    const float* __restrict__ scores, const int* __restrict__ jidx,
    const float* __restrict__ m, const float* __restrict__ den,
    const float* __restrict__ elen, const int* __restrict__ pos,
    unsigned short* __restrict__ Vw) {
  __shared__ float As[128][65];
  int tid = threadIdx.x;
  int e0 = blockIdx.x * 64;
  load_tile(EA, e0, NE, As, tid);
  __syncthreads();
  int ty = tid >> 4, tx = tid & 15;
  float acc[4][8] = {};
  gemm_core(As, WV, ty, tx, acc);
  float4 va = *(const float4*)(bV + tx * 8);
  float4 vb = *(const float4*)(bV + tx * 8 + 4);
  int h = tx >> 1;
#pragma unroll
  for (int r = 0; r < 4; ++r) {
    int e = e0 + ty * 4 + r;
    int jn = jidx[e];
    float s = scores[(size_t)e * NH + h];
    float mm = m[(size_t)jn * NH + h];
    float dd = den[(size_t)jn * NH + h];
    float len = elen[e];
    float phi = 0.5f * (cosf(len * 0.628318530717958647f) + 1.0f);  // pi/5
    float w = __expf(s - mm) / dd * phi;
    float o[8];
    o[0] = (acc[r][0] + va.x) * w; o[1] = (acc[r][1] + va.y) * w;
    o[2] = (acc[r][2] + va.z) * w; o[3] = (acc[r][3] + va.w) * w;
    o[4] = (acc[r][4] + vb.x) * w; o[5] = (acc[r][5] + vb.y) * w;
    o[6] = (acc[r][6] + vb.z) * w; o[7] = (acc[r][7] + vb.w) * w;
    unsigned p0 = f2bf(o[0]) | ((unsigned)f2bf(o[1]) << 16);
    unsigned p1 = f2bf(o[2]) | ((unsigned)f2bf(o[3]) << 16);
    unsigned p2 = f2bf(o[4]) | ((unsigned)f2bf(o[5]) << 16);
    unsigned p3 = f2bf(o[6]) | ((unsigned)f2bf(o[7]) << 16);
    *(uint4*)(Vw + (size_t)pos[e] * D + tx * 8) = make_uint4(p0, p1, p2, p3);
  }
}

// accum[n][:] = sum of CSR-contiguous Vw rows. 64 threads/node (ushort2/lane),
// 4 nodes per 256-block.
__global__ __launch_bounds__(256) void gather_k(const unsigned short* __restrict__ Vw,
    const int* __restrict__ offs, float* __restrict__ accum) {
  int tid = threadIdx.x;
  int n = blockIdx.x * 4 + (tid >> 6);
  int l = tid & 63;
  int o0 = offs[n], o1 = offs[n + 1];
  float a0 = 0.f, a1 = 0.f;
  const unsigned* base = (const unsigned*)Vw;
  for (int s = o0; s < o1; ++s) {
    unsigned u = base[(size_t)s * 64 + l];
    a0 += __uint_as_float(u << 16);
    a1 += __uint_as_float(u & 0xFFFF0000u);
  }
  *(float2*)(accum + (size_t)n * D + l * 2) = make_float2(a0, a1);
}

extern "C" void kernel_launch(void* const* d_in, const int* in_sizes, int n_in,
                              void* d_out, int out_size, void* d_ws, size_t ws_size,
                              hipStream_t stream) {
  const float* x     = (const float*)d_in[0];
  const int*   eidx  = (const int*)d_in[1];
  const int*   jidx  = eidx + NE;
  const float* eattr = (const float*)d_in[2];
  const float* elen  = (const float*)d_in[3];
  const float* W_Q   = (const float*)d_in[4];
  const float* b_Q   = (const float*)d_in[5];
  const float* W_K   = (const float*)d_in[6];
  const float* b_K   = (const float*)d_in[7];
  const float* W_V   = (const float*)d_in[8];
  const float* b_V   = (const float*)d_in[9];
  const float* W_O   = (const float*)d_in[10];
  const float* b_O   = (const float*)d_in[11];
  float* out = (float*)d_out;

  char* ws = (char*)d_ws;
  float* Q      = (float*)ws;                    ws += (size_t)NN * D * 4;
  float* scores = (float*)ws;                    ws += (size_t)NE * NH * 4;
  float* m      = (float*)ws;                    ws += (size_t)NN * NH * 4;
  float* den    = (float*)ws;                    ws += (size_t)NN * NH * 4;
  float* accum  = (float*)ws;                    ws += (size_t)NN * D * 4;
  int*   cnt    = (int*)ws;                      ws += (size_t)NN * 4;
  int*   offs   = (int*)ws;                      ws += (size_t)(NN + 1) * 4;
  int*   cursor = (int*)ws;                      ws += (size_t)NN * 4;
  int*   elist  = (int*)ws;                      ws += (size_t)NE * 4;
  int*   pos    = (int*)ws;                      ws += (size_t)NE * 4;
  unsigned short* Vw = (unsigned short*)ws;      // NE*D bf16 = 204.8 MB

  hipMemsetAsync(cnt, 0, (size_t)NN * 4, stream);

  hist_k<<<NE / 256, 256, 0, stream>>>(jidx, cnt);
  scan_k<<<1, 1024, 0, stream>>>(cnt, offs, cursor);
  scatter_k<<<NE / 256, 256, 0, stream>>>(jidx, cursor, elist, pos);

  gemm_bias_k<<<(NN + 63) / 64, 256, 0, stream>>>(x, W_Q, b_Q, Q, NN);
  kscore_k<<<NE / 64, 256, 0, stream>>>(eattr, W_K, b_K, Q, jidx, scores);
  stats_k<<<NN, 128, 0, stream>>>(scores, offs, elist, m, den);
  vw_k<<<NE / 64, 256, 0, stream>>>(eattr, W_V, b_V, scores, jidx, m, den,
                                    elen, pos, Vw);
  gather_k<<<NN / 4, 256, 0, stream>>>(Vw, offs, accum);
  gemm_bias_k<<<(NN + 63) / 64, 256, 0, stream>>>(accum, W_O, b_O, out, NN);
}